// Round 1
// baseline (885.104 us; speedup 1.0000x reference)
//
#include <hip/hip_runtime.h>
#include <hip/hip_bf16.h>
#include <math.h>

// Problem constants (fixed by setup_inputs)
#define BB 8
#define CC 64
#define HH 128
#define WW 128
#define EE 16
#define DTXT 512
#define HWSZ 16384       // 128*128
#define PAIRS 16         // B * TOP_K

// ws layout:
//   [0, 2048)      pooled[512] fp32
//   [2048, 2112)   eidx[16] int32   (pair -> expert)
//   [2112, 2176)   gval[16] fp32    (pair -> gate)
//   [4096, ...)    h[16][64][128][128] bf16  (33,554,432 bytes)
// total required: ~33.6 MB

static __device__ __forceinline__ unsigned short f2bf(float f) {
  unsigned u = __float_as_uint(f);
  unsigned r = (u + 0x7FFFu + ((u >> 16) & 1u)) >> 16;  // RNE
  return (unsigned short)r;
}
static __device__ __forceinline__ float bf2f(unsigned short s) {
  return __uint_as_float(((unsigned)s) << 16);
}

// ---------------------------------------------------------------- pool
__global__ __launch_bounds__(256) void pool_kernel(const float* __restrict__ x,
                                                   float* __restrict__ pooled) {
  const int bc = blockIdx.x;  // 0..511 = b*64+c
  const float4* p = (const float4*)(x + (size_t)bc * HWSZ);
  float s = 0.f;
  for (int i = threadIdx.x; i < HWSZ / 4; i += 256) {
    float4 v = p[i];
    s += (v.x + v.y) + (v.z + v.w);
  }
#pragma unroll
  for (int off = 32; off > 0; off >>= 1) s += __shfl_down(s, off);
  __shared__ float wsum[4];
  const int wid = threadIdx.x >> 6, lane = threadIdx.x & 63;
  if (lane == 0) wsum[wid] = s;
  __syncthreads();
  if (threadIdx.x == 0)
    pooled[bc] = (wsum[0] + wsum[1] + wsum[2] + wsum[3]) * (1.f / (float)HWSZ);
}

// ---------------------------------------------------------------- gate
__global__ __launch_bounds__(256) void gate_kernel(const float* __restrict__ pooled,
                                                   const float* __restrict__ text,
                                                   const float* __restrict__ Wx,
                                                   const float* __restrict__ Wt,
                                                   int* __restrict__ eidx,
                                                   float* __restrict__ gval,
                                                   float* __restrict__ aux_out) {
  __shared__ float logits[BB][EE];
  __shared__ float gates[BB][EE];
  __shared__ float imp[EE];
  const int t = threadIdx.x;
  if (t < BB * EE) {
    const int b = t >> 4, e = t & 15;
    float s = 0.f;
    for (int c = 0; c < CC; ++c) s += pooled[b * CC + c] * Wx[c * EE + e];
    for (int d = 0; d < DTXT; ++d) s += text[b * DTXT + d] * Wt[d * EE + e];
    logits[b][e] = s;
    gates[b][e] = 0.f;
  }
  __syncthreads();
  if (t < BB) {
    const int b = t;
    float v0 = -1e30f; int i0 = 0;
    for (int e = 0; e < EE; ++e) {
      float v = logits[b][e];
      if (v > v0) { v0 = v; i0 = e; }
    }
    float v1 = -1e30f; int i1 = 0;
    for (int e = 0; e < EE; ++e) {
      if (e == i0) continue;
      float v = logits[b][e];
      if (v > v1) { v1 = v; i1 = e; }
    }
    const float ex = expf(v1 - v0);        // v0 >= v1
    const float g0 = 1.f / (1.f + ex);
    const float g1 = ex / (1.f + ex);
    gates[b][i0] = g0;
    gates[b][i1] = g1;
    eidx[2 * b] = i0;  gval[2 * b] = g0;
    eidx[2 * b + 1] = i1;  gval[2 * b + 1] = g1;
  }
  __syncthreads();
  if (t < EE) {
    float s = 0.f;
    for (int b = 0; b < BB; ++b) s += gates[b][t];
    imp[t] = s;
  }
  __syncthreads();
  if (t == 0) {
    float m = 0.f;
    for (int e = 0; e < EE; ++e) m += imp[e];
    m *= (1.f / EE);
    float v = 0.f;
    for (int e = 0; e < EE; ++e) { float d = imp[e] - m; v += d * d; }
    v *= (1.f / EE);
    aux_out[0] = v / (m * m + 1e-10f);
  }
}

// --------------------------------------------------- conv inner (shared)
// xt: [8][34][35] fp32 (padded stride 35), wt: [8][9][16] fp32
static __device__ __forceinline__ void compute_chunk(const float* __restrict__ xt,
                                                     const float* __restrict__ wt,
                                                     int ly, int lx,
                                                     float acc[2][2][16]) {
  for (int ci = 0; ci < 8; ++ci) {
    float xr[4][4];
#pragma unroll
    for (int r = 0; r < 4; ++r)
#pragma unroll
      for (int c = 0; c < 4; ++c)
        xr[r][c] = xt[ci * (34 * 35) + (ly + r) * 35 + (lx + c)];
#pragma unroll
    for (int kk = 0; kk < 9; ++kk) {
      const float4 wa = *(const float4*)(wt + ci * 144 + kk * 16 + 0);
      const float4 wb = *(const float4*)(wt + ci * 144 + kk * 16 + 4);
      const float4 wc = *(const float4*)(wt + ci * 144 + kk * 16 + 8);
      const float4 wd = *(const float4*)(wt + ci * 144 + kk * 16 + 12);
      const int kh = kk / 3, kw = kk % 3;
#pragma unroll
      for (int dy = 0; dy < 2; ++dy)
#pragma unroll
        for (int dx = 0; dx < 2; ++dx) {
          const float xv = xr[dy + kh][dx + kw];
          acc[dy][dx][0]  += wa.x * xv;  acc[dy][dx][1]  += wa.y * xv;
          acc[dy][dx][2]  += wa.z * xv;  acc[dy][dx][3]  += wa.w * xv;
          acc[dy][dx][4]  += wb.x * xv;  acc[dy][dx][5]  += wb.y * xv;
          acc[dy][dx][6]  += wb.z * xv;  acc[dy][dx][7]  += wb.w * xv;
          acc[dy][dx][8]  += wc.x * xv;  acc[dy][dx][9]  += wc.y * xv;
          acc[dy][dx][10] += wc.z * xv;  acc[dy][dx][11] += wc.w * xv;
          acc[dy][dx][12] += wd.x * xv;  acc[dy][dx][13] += wd.y * xv;
          acc[dy][dx][14] += wd.z * xv;  acc[dy][dx][15] += wd.w * xv;
        }
    }
  }
}

// ---------------------------------------------------------------- conv1
// grid: (tile=16, cogroup=4, pair=16), block 256.  out: h (bf16) = gelu(conv1(x)+b1)
__global__ __launch_bounds__(256) void conv1_kernel(const float* __restrict__ x,
                                                    const float* __restrict__ w1,
                                                    const float* __restrict__ b1,
                                                    const int* __restrict__ eidx,
                                                    unsigned short* __restrict__ h) {
  __shared__ float xt[8 * 34 * 35];
  __shared__ float wt[8 * 9 * 16];
  const int tid = threadIdx.x;
  const int tile = blockIdx.x;
  const int cog = blockIdx.y;
  const int p = blockIdx.z;
  const int e = eidx[p];
  const int b = p >> 1;
  const int co0 = cog * 16;
  const int ty0 = (tile >> 2) * 32, tx0 = (tile & 3) * 32;
  const int thy = tid >> 4, thx = tid & 15;
  const int ly = thy * 2, lx = thx * 2;

  float acc[2][2][16];
#pragma unroll
  for (int co = 0; co < 16; ++co) {
    const float bv = b1[e * CC + co0 + co];
    acc[0][0][co] = bv; acc[0][1][co] = bv; acc[1][0][co] = bv; acc[1][1][co] = bv;
  }

  const float* xb = x + (size_t)b * CC * HWSZ;

  for (int ch = 0; ch < 8; ++ch) {
    const int ci0 = ch * 8;
    __syncthreads();
    for (int idx = tid; idx < 8 * 34 * 34; idx += 256) {
      const int ci = idx / 1156;
      const int r = idx - ci * 1156;
      const int yy = r / 34;
      const int xx = r - yy * 34;
      const int gy = ty0 - 1 + yy, gx = tx0 - 1 + xx;
      float v = 0.f;
      if ((unsigned)gy < (unsigned)HH && (unsigned)gx < (unsigned)WW)
        v = xb[(ci0 + ci) * HWSZ + gy * WW + gx];
      xt[ci * (34 * 35) + yy * 35 + xx] = v;
    }
    for (int idx = tid; idx < 8 * 9 * 16; idx += 256) {
      const int ci = idx / 144;
      const int r = idx - ci * 144;
      const int k = r >> 4;
      const int co = r & 15;
      wt[idx] = w1[(((size_t)e * CC + co0 + co) * CC + ci0 + ci) * 9 + k];
    }
    __syncthreads();
    compute_chunk(xt, wt, ly, lx, acc);
  }

  // epilogue: exact GELU, store bf16 pairs
#pragma unroll
  for (int co = 0; co < 16; ++co) {
    unsigned short* hb = h + ((size_t)p * CC + co0 + co) * HWSZ;
#pragma unroll
    for (int dy = 0; dy < 2; ++dy) {
      const int gy = ty0 + ly + dy, gx = tx0 + lx;
      float v0 = acc[dy][0][co], v1 = acc[dy][1][co];
      v0 = 0.5f * v0 * (1.f + erff(v0 * 0.70710678118654752f));
      v1 = 0.5f * v1 * (1.f + erff(v1 * 0.70710678118654752f));
      const unsigned packed = (unsigned)f2bf(v0) | ((unsigned)f2bf(v1) << 16);
      *(unsigned*)(hb + gy * WW + gx) = packed;
    }
  }
}

// ---------------------------------------------------------------- conv2
// grid: (tile=16, cogroup=4, b=8), block 256. Loops both slots; gate folded into weights.
__global__ __launch_bounds__(256) void conv2_kernel(const unsigned short* __restrict__ h,
                                                    const float* __restrict__ w2,
                                                    const float* __restrict__ b2,
                                                    const int* __restrict__ eidx,
                                                    const float* __restrict__ gval,
                                                    float* __restrict__ out) {
  __shared__ float xt[8 * 34 * 35];
  __shared__ float wt[8 * 9 * 16];
  const int tid = threadIdx.x;
  const int tile = blockIdx.x;
  const int cog = blockIdx.y;
  const int b = blockIdx.z;
  const int co0 = cog * 16;
  const int ty0 = (tile >> 2) * 32, tx0 = (tile & 3) * 32;
  const int thy = tid >> 4, thx = tid & 15;
  const int ly = thy * 2, lx = thx * 2;

  float acc[2][2][16];
#pragma unroll
  for (int dy = 0; dy < 2; ++dy)
#pragma unroll
    for (int dx = 0; dx < 2; ++dx)
#pragma unroll
      for (int co = 0; co < 16; ++co) acc[dy][dx][co] = 0.f;

  for (int slot = 0; slot < 2; ++slot) {
    const int p = b * 2 + slot;
    const int e = eidx[p];
    const float g = gval[p];
    const unsigned short* hb = h + (size_t)p * CC * HWSZ;

    for (int ch = 0; ch < 8; ++ch) {
      const int ci0 = ch * 8;
      __syncthreads();
      for (int idx = tid; idx < 8 * 34 * 34; idx += 256) {
        const int ci = idx / 1156;
        const int r = idx - ci * 1156;
        const int yy = r / 34;
        const int xx = r - yy * 34;
        const int gy = ty0 - 1 + yy, gx = tx0 - 1 + xx;
        float v = 0.f;
        if ((unsigned)gy < (unsigned)HH && (unsigned)gx < (unsigned)WW)
          v = bf2f(hb[(ci0 + ci) * HWSZ + gy * WW + gx]);
        xt[ci * (34 * 35) + yy * 35 + xx] = v;
      }
      for (int idx = tid; idx < 8 * 9 * 16; idx += 256) {
        const int ci = idx / 144;
        const int r = idx - ci * 144;
        const int k = r >> 4;
        const int co = r & 15;
        wt[idx] = g * w2[(((size_t)e * CC + co0 + co) * CC + ci0 + ci) * 9 + k];
      }
      __syncthreads();
      compute_chunk(xt, wt, ly, lx, acc);
    }
  }

  // gated bias sum
  const int e0 = eidx[2 * b], e1 = eidx[2 * b + 1];
  const float g0 = gval[2 * b], g1 = gval[2 * b + 1];

#pragma unroll
  for (int co = 0; co < 16; ++co) {
    const float bsum = g0 * b2[e0 * CC + co0 + co] + g1 * b2[e1 * CC + co0 + co];
    float* ob = out + ((size_t)b * CC + co0 + co) * HWSZ;
#pragma unroll
    for (int dy = 0; dy < 2; ++dy) {
      const int gy = ty0 + ly + dy, gx = tx0 + lx;
      float2 v;
      v.x = acc[dy][0][co] + bsum;
      v.y = acc[dy][1][co] + bsum;
      *(float2*)(ob + gy * WW + gx) = v;
    }
  }
}

// ---------------------------------------------------------------- launch
extern "C" void kernel_launch(void* const* d_in, const int* in_sizes, int n_in,
                              void* d_out, int out_size, void* d_ws, size_t ws_size,
                              hipStream_t stream) {
  const float* x   = (const float*)d_in[0];
  const float* txt = (const float*)d_in[1];
  const float* Wx  = (const float*)d_in[2];
  const float* Wt  = (const float*)d_in[3];
  const float* w1  = (const float*)d_in[4];
  const float* b1  = (const float*)d_in[5];
  const float* w2  = (const float*)d_in[6];
  const float* b2  = (const float*)d_in[7];
  float* out = (float*)d_out;

  char* ws = (char*)d_ws;
  float* pooled = (float*)ws;
  int* eidx = (int*)(ws + 2048);
  float* gval = (float*)(ws + 2112);
  unsigned short* h = (unsigned short*)(ws + 4096);

  pool_kernel<<<512, 256, 0, stream>>>(x, pooled);
  gate_kernel<<<1, 256, 0, stream>>>(pooled, txt, Wx, Wt, eidx, gval,
                                     out + (out_size - 1));
  conv1_kernel<<<dim3(16, 4, 16), 256, 0, stream>>>(x, w1, b1, eidx, h);
  conv2_kernel<<<dim3(16, 4, 8), 256, 0, stream>>>(h, w2, b2, eidx, gval, out);
}

// Round 2
// 130.838 us; speedup vs baseline: 6.7649x; 6.7649x over previous
//
#include <hip/hip_runtime.h>
#include <hip/hip_bf16.h>
#include <math.h>

typedef __attribute__((ext_vector_type(8))) short      bf16x8;
typedef __attribute__((ext_vector_type(8))) unsigned short u16x8;
typedef __attribute__((ext_vector_type(4))) unsigned short u16x4;
typedef __attribute__((ext_vector_type(4))) float       f32x4;

#define BB 8
#define CC 64
#define HH 128
#define WW 128
#define EE 16
#define DTXT 512
#define HWSZ 16384
#define NPAIR 16

// conv tile geometry
#define TH 16
#define TW 32
#define HR 18
#define HC 34
#define HPX (HR * HC)          // 612 halo pixels
#define XCHUNKS (HPX * 8)      // 4896 16B chunks of x tile
#define WCHUNKS 4608           // 2chunk * 9k * 4slot * 64co 16B chunks

static __device__ __forceinline__ unsigned short f2bf(float f) {
  unsigned u = __float_as_uint(f);
  unsigned r = (u + 0x7FFFu + ((u >> 16) & 1u)) >> 16;  // RNE
  return (unsigned short)r;
}

// ---------------------------------------------------------------- pool
__global__ __launch_bounds__(256) void pool_kernel(const float* __restrict__ x,
                                                   float* __restrict__ pooled) {
  const int bc = blockIdx.x;
  const float4* p = (const float4*)(x + (size_t)bc * HWSZ);
  float s = 0.f;
  for (int i = threadIdx.x; i < HWSZ / 4; i += 256) {
    float4 v = p[i];
    s += (v.x + v.y) + (v.z + v.w);
  }
#pragma unroll
  for (int off = 32; off > 0; off >>= 1) s += __shfl_down(s, off);
  __shared__ float wsum[4];
  const int wid = threadIdx.x >> 6, lane = threadIdx.x & 63;
  if (lane == 0) wsum[wid] = s;
  __syncthreads();
  if (threadIdx.x == 0)
    pooled[bc] = (wsum[0] + wsum[1] + wsum[2] + wsum[3]) * (1.f / (float)HWSZ);
}

// ---------------------------------------------------------------- gate
__global__ __launch_bounds__(256) void gate_kernel(const float* __restrict__ pooled,
                                                   const float* __restrict__ text,
                                                   const float* __restrict__ Wx,
                                                   const float* __restrict__ Wt,
                                                   int* __restrict__ eidx,
                                                   float* __restrict__ gval,
                                                   float* __restrict__ aux_out) {
  __shared__ float logits[BB][EE];
  __shared__ float gates[BB][EE];
  __shared__ float imp[EE];
  const int t = threadIdx.x;
  if (t < BB * EE) {
    const int b = t >> 4, e = t & 15;
    float s = 0.f;
    for (int c = 0; c < CC; ++c) s += pooled[b * CC + c] * Wx[c * EE + e];
    for (int d = 0; d < DTXT; ++d) s += text[b * DTXT + d] * Wt[d * EE + e];
    logits[b][e] = s;
    gates[b][e] = 0.f;
  }
  __syncthreads();
  if (t < BB) {
    const int b = t;
    float v0 = -1e30f; int i0 = 0;
    for (int e = 0; e < EE; ++e) {
      float v = logits[b][e];
      if (v > v0) { v0 = v; i0 = e; }
    }
    float v1 = -1e30f; int i1 = 0;
    for (int e = 0; e < EE; ++e) {
      if (e == i0) continue;
      float v = logits[b][e];
      if (v > v1) { v1 = v; i1 = e; }
    }
    const float ex = expf(v1 - v0);
    const float g0 = 1.f / (1.f + ex);
    const float g1 = ex / (1.f + ex);
    gates[b][i0] = g0;
    gates[b][i1] = g1;
    eidx[2 * b] = i0;      gval[2 * b] = g0;
    eidx[2 * b + 1] = i1;  gval[2 * b + 1] = g1;
  }
  __syncthreads();
  if (t < EE) {
    float s = 0.f;
    for (int b = 0; b < BB; ++b) s += gates[b][t];
    imp[t] = s;
  }
  __syncthreads();
  if (t == 0) {
    float m = 0.f;
    for (int e = 0; e < EE; ++e) m += imp[e];
    m *= (1.f / EE);
    float v = 0.f;
    for (int e = 0; e < EE; ++e) { float d = imp[e] - m; v += d * d; }
    v *= (1.f / EE);
    aux_out[0] = v / (m * m + 1e-10f);
  }
}

// ---------------------------------------------------------------- xtprep
// x[b][ci][px] fp32 -> xT[b][px][ci] bf16. block: (pxblk, b), 256 thr.
__global__ __launch_bounds__(256) void xtprep_kernel(const float* __restrict__ x,
                                                     unsigned short* __restrict__ xT) {
  __shared__ unsigned short lt[256 * 70];
  const int b = blockIdx.y, p0 = blockIdx.x * 256;
  const int t = threadIdx.x;
  const float* xb = x + (size_t)b * CC * HWSZ + p0;
#pragma unroll 8
  for (int ci = 0; ci < CC; ++ci)
    lt[t * 70 + ci] = f2bf(xb[(size_t)ci * HWSZ + t]);
  __syncthreads();
  unsigned short* dstb = xT + ((size_t)b * HWSZ + p0) * CC;
#pragma unroll
  for (int it = 0; it < 8; ++it) {
    const int j = it * 256 + t;
    const int px = j >> 3, s = j & 7;
    u16x8 v;
#pragma unroll
    for (int i = 0; i < 8; ++i) v[i] = lt[px * 70 + s * 8 + i];
    *(u16x8*)(dstb + (size_t)j * 8) = v;
  }
}

// ---------------------------------------------------------------- wprep
// repack selected experts' conv weights into MFMA fragment order:
// wp[pair][chunk2][k9][slot4][co64][8ci] bf16; gate folded into wp2.
__global__ __launch_bounds__(256) void wprep_kernel(const float* __restrict__ w1,
                                                    const float* __restrict__ w2,
                                                    const int* __restrict__ eidx,
                                                    const float* __restrict__ gval,
                                                    unsigned short* __restrict__ wp1,
                                                    unsigned short* __restrict__ wp2) {
  const int p = blockIdx.x;
  const int conv = blockIdx.y;
  const int e = eidx[p];
  const float g = conv ? gval[p] : 1.0f;
  const float* wsrc = (conv ? w2 : w1) + (size_t)e * CC * CC * 9;
  unsigned short* dst = (conv ? wp2 : wp1) + (size_t)p * WCHUNKS * 8;
  for (int c16 = threadIdx.x; c16 < WCHUNKS; c16 += 256) {
    const int co = c16 & 63;
    const int rest = c16 >> 6;
    const int s = rest & 3;
    const int ck = rest >> 2;
    const int k = ck % 9, chunk = ck / 9;
    const int ci0 = chunk * 32 + s * 8;
    u16x8 v;
#pragma unroll
    for (int i = 0; i < 8; ++i)
      v[i] = f2bf(g * wsrc[((size_t)co * CC + ci0 + i) * 9 + k]);
    *(u16x8*)(dst + (size_t)c16 * 8) = v;
  }
}

// ------------------------------------------------- conv core helpers
static __device__ __forceinline__ void stage_tile(const u16x8* __restrict__ src,
                                                  const u16x8* __restrict__ wsrc,
                                                  u16x8* xt, u16x8* wt,
                                                  int ty0, int tx0, int t) {
  // weights: 4608 chunks / 512 thr = 9 iters, linear copy
#pragma unroll
  for (int i = 0; i < 9; ++i) {
    const int idx = i * 512 + t;
    wt[idx] = wsrc[idx];
  }
  // x halo tile: 4896 chunks, zero-padded OOB, XOR-swizzled dest
#pragma unroll
  for (int i = 0; i < 10; ++i) {
    const int idx = i * 512 + t;
    if (idx < XCHUNKS) {
      const int ph = idx >> 3, s = idx & 7;
      const int yy = ph / HC, xx = ph - yy * HC;
      const int gy = ty0 - 1 + yy, gx = tx0 - 1 + xx;
      u16x8 v = (u16x8){0, 0, 0, 0, 0, 0, 0, 0};
      if ((unsigned)gy < (unsigned)HH && (unsigned)gx < (unsigned)WW)
        v = src[(gy * WW + gx) * 8 + s];
      xt[ph * 8 + (s ^ (ph & 7))] = v;
    }
  }
}

static __device__ __forceinline__ void conv_compute(const u16x8* xt, const u16x8* wt,
                                                    int lane, int w, f32x4 acc[4][4]) {
  const int ks = lane >> 4;      // k-slot 0..3
  const int ln = lane & 15;
#pragma unroll
  for (int chunk = 0; chunk < 2; ++chunk) {
#pragma unroll
    for (int kk = 0; kk < 9; ++kk) {
      const int dy = kk / 3, dx = kk % 3;
      bf16x8 a[4];
#pragma unroll
      for (int mf = 0; mf < 4; ++mf)
        a[mf] = __builtin_bit_cast(bf16x8,
                  wt[((chunk * 9 + kk) * 4 + ks) * 64 + mf * 16 + ln]);
#pragma unroll
      for (int nf = 0; nf < 4; ++nf) {
        const int row = 2 * w + (nf >> 1) + dy;
        const int col = (nf & 1) * 16 + ln + dx;
        const int ph = row * HC + col;
        const bf16x8 bfr = __builtin_bit_cast(bf16x8,
                  xt[ph * 8 + ((chunk * 4 + ks) ^ (ph & 7))]);
#pragma unroll
        for (int mf = 0; mf < 4; ++mf)
          acc[nf][mf] = __builtin_amdgcn_mfma_f32_16x16x32_bf16(a[mf], bfr,
                                                                acc[nf][mf], 0, 0, 0);
      }
    }
  }
}

// ---------------------------------------------------------------- conv1
// grid (32 tiles, 16 pairs), 512 thr. h[pair][px][64co] bf16 = gelu(conv(x)+b1)
__global__ __launch_bounds__(512, 2) void conv1_kernel(const u16x8* __restrict__ xT,
                                                       const u16x8* __restrict__ wp1,
                                                       const float* __restrict__ b1,
                                                       const int* __restrict__ eidx,
                                                       unsigned short* __restrict__ h) {
  __shared__ u16x8 xt[HPX * 8];
  __shared__ u16x8 wt[WCHUNKS];
  const int t = threadIdx.x, lane = t & 63, w = t >> 6;
  const int tile = blockIdx.x, p = blockIdx.y;
  const int b = p >> 1, e = eidx[p];
  const int ty0 = (tile >> 2) * TH, tx0 = (tile & 3) * TW;

  f32x4 acc[4][4];
#pragma unroll
  for (int i = 0; i < 4; ++i)
#pragma unroll
    for (int j = 0; j < 4; ++j) acc[i][j] = (f32x4){0.f, 0.f, 0.f, 0.f};

  stage_tile(xT + (size_t)b * HWSZ * 8, wp1 + (size_t)p * WCHUNKS, xt, wt, ty0, tx0, t);
  __syncthreads();
  conv_compute(xt, wt, lane, w, acc);

  const int co_s = (lane >> 4) * 4;
  const int ln = lane & 15;
#pragma unroll
  for (int mf = 0; mf < 4; ++mf) {
    const float4 bv = *(const float4*)(b1 + e * CC + mf * 16 + co_s);
#pragma unroll
    for (int nf = 0; nf < 4; ++nf) {
      const int row = 2 * w + (nf >> 1), col = (nf & 1) * 16 + ln;
      const int gpx = (ty0 + row) * WW + tx0 + col;
      f32x4 v = acc[nf][mf];
      float r0 = v.x + bv.x, r1 = v.y + bv.y, r2 = v.z + bv.z, r3 = v.w + bv.w;
      r0 = 0.5f * r0 * (1.f + erff(r0 * 0.70710678118654752f));
      r1 = 0.5f * r1 * (1.f + erff(r1 * 0.70710678118654752f));
      r2 = 0.5f * r2 * (1.f + erff(r2 * 0.70710678118654752f));
      r3 = 0.5f * r3 * (1.f + erff(r3 * 0.70710678118654752f));
      u16x4 pk = {f2bf(r0), f2bf(r1), f2bf(r2), f2bf(r3)};
      *(u16x4*)(h + ((size_t)p * HWSZ + gpx) * CC + mf * 16 + co_s) = pk;
    }
  }
}

// ---------------------------------------------------------------- conv2
// grid (32 tiles, 8 batch), 512 thr. out[b][co][px] fp32, gated biases.
__global__ __launch_bounds__(512, 2) void conv2_kernel(const u16x8* __restrict__ h,
                                                       const u16x8* __restrict__ wp2,
                                                       const float* __restrict__ b2,
                                                       const int* __restrict__ eidx,
                                                       const float* __restrict__ gval,
                                                       float* __restrict__ out) {
  __shared__ u16x8 xt[HPX * 8];
  __shared__ u16x8 wt[WCHUNKS];
  const int t = threadIdx.x, lane = t & 63, w = t >> 6;
  const int tile = blockIdx.x, b = blockIdx.y;
  const int ty0 = (tile >> 2) * TH, tx0 = (tile & 3) * TW;

  f32x4 acc[4][4];
#pragma unroll
  for (int i = 0; i < 4; ++i)
#pragma unroll
    for (int j = 0; j < 4; ++j) acc[i][j] = (f32x4){0.f, 0.f, 0.f, 0.f};

#pragma unroll
  for (int slot = 0; slot < 2; ++slot) {
    const int p = 2 * b + slot;
    if (slot) __syncthreads();
    stage_tile(h + (size_t)p * HWSZ * 8, wp2 + (size_t)p * WCHUNKS, xt, wt, ty0, tx0, t);
    __syncthreads();
    conv_compute(xt, wt, lane, w, acc);
  }

  const int e0 = eidx[2 * b], e1 = eidx[2 * b + 1];
  const float g0 = gval[2 * b], g1 = gval[2 * b + 1];
  const int co_s = (lane >> 4) * 4;
  const int ln = lane & 15;
#pragma unroll
  for (int mf = 0; mf < 4; ++mf) {
    const float4 ba = *(const float4*)(b2 + e0 * CC + mf * 16 + co_s);
    const float4 bb = *(const float4*)(b2 + e1 * CC + mf * 16 + co_s);
    const float bx = g0 * ba.x + g1 * bb.x;
    const float by = g0 * ba.y + g1 * bb.y;
    const float bz = g0 * ba.z + g1 * bb.z;
    const float bw = g0 * ba.w + g1 * bb.w;
#pragma unroll
    for (int nf = 0; nf < 4; ++nf) {
      const int row = 2 * w + (nf >> 1), col = (nf & 1) * 16 + ln;
      const int gpx = (ty0 + row) * WW + tx0 + col;
      f32x4 v = acc[nf][mf];
      float* ob = out + (size_t)(b * CC + mf * 16 + co_s) * HWSZ + gpx;
      ob[0 * HWSZ] = v.x + bx;
      ob[1 * HWSZ] = v.y + by;
      ob[2 * HWSZ] = v.z + bz;
      ob[3 * HWSZ] = v.w + bw;
    }
  }
}

// ---------------------------------------------------------------- launch
extern "C" void kernel_launch(void* const* d_in, const int* in_sizes, int n_in,
                              void* d_out, int out_size, void* d_ws, size_t ws_size,
                              hipStream_t stream) {
  const float* x   = (const float*)d_in[0];
  const float* txt = (const float*)d_in[1];
  const float* Wx  = (const float*)d_in[2];
  const float* Wt  = (const float*)d_in[3];
  const float* w1  = (const float*)d_in[4];
  const float* b1  = (const float*)d_in[5];
  const float* w2  = (const float*)d_in[6];
  const float* b2  = (const float*)d_in[7];
  float* out = (float*)d_out;

  char* ws = (char*)d_ws;
  float* pooled = (float*)ws;                      // 2048 B
  int*   eidx   = (int*)(ws + 2048);               // 64 B
  float* gval   = (float*)(ws + 2112);             // 64 B
  unsigned short* wp1 = (unsigned short*)(ws + 4096);        // 1,179,648 B
  unsigned short* wp2 = (unsigned short*)(ws + 1183744);     // 1,179,648 B
  unsigned short* xT  = (unsigned short*)(ws + 2363392);     // 16,777,216 B
  unsigned short* h   = (unsigned short*)(ws + 19140608);    // 33,554,432 B

  pool_kernel<<<512, 256, 0, stream>>>(x, pooled);
  gate_kernel<<<1, 256, 0, stream>>>(pooled, txt, Wx, Wt, eidx, gval,
                                     out + (out_size - 1));
  xtprep_kernel<<<dim3(64, 8), 256, 0, stream>>>(x, xT);
  wprep_kernel<<<dim3(16, 2), 256, 0, stream>>>(w1, w2, eidx, gval, wp1, wp2);
  conv1_kernel<<<dim3(32, 16), 512, 0, stream>>>((const u16x8*)xT, (const u16x8*)wp1,
                                                 b1, eidx, (unsigned short*)h);
  conv2_kernel<<<dim3(32, 8), 512, 0, stream>>>((const u16x8*)h, (const u16x8*)wp2,
                                                b2, eidx, gval, out);
}